// Round 1
// baseline (94.650 us; speedup 1.0000x reference)
//
#include <hip/hip_runtime.h>

typedef float f4 __attribute__((ext_vector_type(4)));

static __device__ __forceinline__ f4 vmax4(f4 a, f4 b) {
  f4 r;
  r.x = fmaxf(a.x, b.x); r.y = fmaxf(a.y, b.y);
  r.z = fmaxf(a.z, b.z); r.w = fmaxf(a.w, b.w);
  return r;
}
static __device__ __forceinline__ f4 vexp2(f4 a) {
  f4 r;
  r.x = exp2f(a.x); r.y = exp2f(a.y);
  r.z = exp2f(a.z); r.w = exp2f(a.w);
  return r;
}
static __device__ __forceinline__ float hsum(f4 v) {
  return (v.x + v.y) + (v.z + v.w);
}

// One block per (b, h). 256 threads: lane w = t & 127 (coalesced), cg = t >> 7.
// Each thread computes out[b, c, h, w] for 32 channels c = cg*32 .. cg*32+31.
__global__ __launch_bounds__(256) void stem_kernel(
    const float* __restrict__ x,    // [8,3,128,128]
    const float* __restrict__ qwp,  // [64,3]
    const float* __restrict__ kwp,  // [64,3]
    const float* __restrict__ vwp,  // [64,3]
    const float* __restrict__ ea,   // [64,128]  (c, w)
    const float* __restrict__ eb,   // [64,128]  (c, h)
    const float* __restrict__ em,   // [64,128,128] (c, h, w)
    float* __restrict__ out)        // [8,64,128,128]
{
  // xt[cin][wp][r]: padded col wp in [0,132), r = 0..3 <-> source row h-2+r
  // innermost dim 4 floats -> 16B aligned float4 per (cin,wp)
  __shared__ float xt[3][132][4];

  const int blk = blockIdx.x;
  const int b = blk >> 7;
  const int h = blk & 127;
  const int t = threadIdx.x;

  // Stage: coalesced reads of the 12 source rows (3 cin x 4 rows), zero-padded.
  for (int idx = t; idx < 3 * 4 * 132; idx += 256) {
    int wp  = idx % 132;
    int rem = idx / 132;      // cin*4 + r
    int rr  = rem & 3;
    int cin = rem >> 2;
    int sr = h - 2 + rr;
    int sc = wp - 2;
    float val = 0.0f;
    if ((unsigned)sr < 128u && (unsigned)sc < 128u)
      val = x[((b * 3 + cin) * 128 + sr) * 128 + sc];
    xt[cin][wp][rr] = val;
  }
  __syncthreads();

  const int w  = t & 127;
  const int cg = t >> 7;                 // wave-uniform (0 for waves 0-1, 1 for waves 2-3)
  const float LOG2E = 1.4426950408889634f;

  // x window for this w: cols w..w+3, rows 0..3, 3 cin. Loaded once, reused for 32 c.
  f4 xw0[4], xw1[4], xw2[4];
#pragma unroll
  for (int j = 0; j < 4; ++j) {
    xw0[j] = *(const f4*)(&xt[0][w + j][0]);
    xw1[j] = *(const f4*)(&xt[1][w + j][0]);
    xw2[j] = *(const f4*)(&xt[2][w + j][0]);
  }

  const int base_c = cg * 32;
  for (int i = 0; i < 32; ++i) {
    const int c = __builtin_amdgcn_readfirstlane(base_c + i);  // wave-uniform -> s_loads

    const float kwa = kwp[c * 3 + 0], kwb = kwp[c * 3 + 1], kwc = kwp[c * 3 + 2];
    const float vwa = vwp[c * 3 + 0], vwb = vwp[c * 3 + 1], vwc = vwp[c * 3 + 2];
    const float qwa = qwp[c * 3 + 0], qwb = qwp[c * 3 + 1], qwc = qwp[c * 3 + 2];

    // k,v taps: kk[j][i_row] = conv at (padded row h+i, padded col w+j)
    f4 kk[4], vv[4];
#pragma unroll
    for (int j = 0; j < 4; ++j) {
      kk[j] = kwa * xw0[j] + kwb * xw1[j] + kwc * xw2[j];
      vv[j] = vwa * xw0[j] + vwb * xw1[j] + vwc * xw2[j];
    }
    // q at (h,w) = x row r=2, padded col w+2 -> component .z of col j=2
    const float q = qwa * xw0[2].z + qwb * xw1[2].z + qwc * xw2[2].z;

    // s' = (ea + eb) * em * log2(e)   (scalar per output, shared by 16 taps)
    const float sp =
        (ea[c * 128 + w] + eb[c * 128 + h]) * em[(c * 128 + h) * 128 + w] * LOG2E;

    // embedding logits (log2 domain): tl = s' * v^2
    f4 tl[4];
#pragma unroll
    for (int j = 0; j < 4; ++j) tl[j] = (sp * vv[j]) * vv[j];

    f4 mm = vmax4(vmax4(tl[0], tl[1]), vmax4(tl[2], tl[3]));
    const float tmax = fmaxf(fmaxf(mm.x, mm.y), fmaxf(mm.z, mm.w));

    // e_t = 2^(tl - tmax); normalization folded into q below
    f4 e[4];
#pragma unroll
    for (int j = 0; j < 4; ++j) e[j] = vexp2(tl[j] - tmax);

    const float sum_e = hsum((e[0] + e[1]) + (e[2] + e[3]));
    const float qs = q * LOG2E * __builtin_amdgcn_rcpf(sum_e);

    // att logits z = qs * k * e  (|z| <~ 4 -> no max-subtraction needed)
    f4 p[4];
#pragma unroll
    for (int j = 0; j < 4; ++j) p[j] = vexp2((qs * kk[j]) * e[j]);

    f4 ps4 = (p[0] + p[1]) + (p[2] + p[3]);
    f4 pv4 = p[0] * vv[0] + p[1] * vv[1];
    pv4 = pv4 + (p[2] * vv[2] + p[3] * vv[3]);

    const float denom = hsum(ps4);
    const float numer = hsum(pv4);

    out[((b * 64 + c) * 128 + h) * 128 + w] =
        numer * __builtin_amdgcn_rcpf(denom);
  }
}

extern "C" void kernel_launch(void* const* d_in, const int* in_sizes, int n_in,
                              void* d_out, int out_size, void* d_ws, size_t ws_size,
                              hipStream_t stream) {
  const float* x  = (const float*)d_in[0];
  const float* qw = (const float*)d_in[1];
  const float* kw = (const float*)d_in[2];
  const float* vw = (const float*)d_in[3];
  const float* ea = (const float*)d_in[4];
  const float* eb = (const float*)d_in[5];
  const float* em = (const float*)d_in[6];
  float* out = (float*)d_out;

  stem_kernel<<<dim3(8 * 128), dim3(256), 0, stream>>>(x, qw, kw, vw, ea, eb, em, out);
}

// Round 2
// 62.340 us; speedup vs baseline: 1.5183x; 1.5183x over previous
//
#include <hip/hip_runtime.h>

typedef float f4 __attribute__((ext_vector_type(4)));

static __device__ __forceinline__ f4 vmax4(f4 a, f4 b) {
  f4 r;
  r.x = fmaxf(a.x, b.x); r.y = fmaxf(a.y, b.y);
  r.z = fmaxf(a.z, b.z); r.w = fmaxf(a.w, b.w);
  return r;
}
// native v_exp_f32 per component (inputs are well inside normal range)
static __device__ __forceinline__ f4 vexp2(f4 a) {
  f4 r;
  r.x = __builtin_amdgcn_exp2f(a.x); r.y = __builtin_amdgcn_exp2f(a.y);
  r.z = __builtin_amdgcn_exp2f(a.z); r.w = __builtin_amdgcn_exp2f(a.w);
  return r;
}
static __device__ __forceinline__ float hsum(f4 v) {
  return (v.x + v.y) + (v.z + v.w);
}

// One block per (b, h). 256 threads: lane w = t & 127 (coalesced), cg = t >> 7.
// Each thread computes out[b, c, h, w] for 32 channels c = cg*32 .. cg*32+31.
// launch_bounds(256, 4): grid is 1024 blocks = 4 blocks/CU; allow 128 VGPRs so
// the 48-reg x-window stays register-resident across the channel loop.
__global__ __launch_bounds__(256, 4) void stem_kernel(
    const float* __restrict__ x,    // [8,3,128,128]
    const float* __restrict__ qwp,  // [64,3]
    const float* __restrict__ kwp,  // [64,3]
    const float* __restrict__ vwp,  // [64,3]
    const float* __restrict__ ea,   // [64,128]  (c, w)
    const float* __restrict__ eb,   // [64,128]  (c, h)
    const float* __restrict__ em,   // [64,128,128] (c, h, w)
    float* __restrict__ out)        // [8,64,128,128]
{
  // xt[cin][wp][r]: padded col wp in [0,132), r = 0..3 <-> source row h-2+r
  __shared__ float xt[3][132][4];

  const int blk = blockIdx.x;
  const int b = blk >> 7;
  const int h = blk & 127;
  const int t = threadIdx.x;

  // Stage: coalesced reads of the 12 source rows (3 cin x 4 rows), zero-padded.
  for (int idx = t; idx < 3 * 4 * 132; idx += 256) {
    int wp  = idx % 132;
    int rem = idx / 132;      // cin*4 + r
    int rr  = rem & 3;
    int cin = rem >> 2;
    int sr = h - 2 + rr;
    int sc = wp - 2;
    float val = 0.0f;
    if ((unsigned)sr < 128u && (unsigned)sc < 128u)
      val = x[((b * 3 + cin) * 128 + sr) * 128 + sc];
    xt[cin][wp][rr] = val;
  }
  __syncthreads();

  const int w  = t & 127;
  const int cg = t >> 7;                 // wave-uniform
  const float LOG2E = 1.4426950408889634f;

  // x window for this w: cols w..w+3, rows 0..3, 3 cin. Loaded once, reused for 32 c.
  f4 xw0[4], xw1[4], xw2[4];
#pragma unroll
  for (int j = 0; j < 4; ++j) {
    xw0[j] = *(const f4*)(&xt[0][w + j][0]);
    xw1[j] = *(const f4*)(&xt[1][w + j][0]);
    xw2[j] = *(const f4*)(&xt[2][w + j][0]);
  }

  const int base_c = cg * 32;
#pragma unroll 1
  for (int i = 0; i < 32; ++i) {
    const int c = __builtin_amdgcn_readfirstlane(base_c + i);  // wave-uniform -> s_loads

    const float kwa = kwp[c * 3 + 0], kwb = kwp[c * 3 + 1], kwc = kwp[c * 3 + 2];
    const float vwa = vwp[c * 3 + 0], vwb = vwp[c * 3 + 1], vwc = vwp[c * 3 + 2];
    const float qwa = qwp[c * 3 + 0], qwb = qwp[c * 3 + 1], qwc = qwp[c * 3 + 2];

    // k,v taps: kk[j][r] = conv at (padded row h+r, padded col w+j)
    f4 kk[4], vv[4];
#pragma unroll
    for (int j = 0; j < 4; ++j) {
      kk[j] = kwa * xw0[j] + kwb * xw1[j] + kwc * xw2[j];
      vv[j] = vwa * xw0[j] + vwb * xw1[j] + vwc * xw2[j];
    }
    // q at (h,w) = row r=2 of padded col w+2 -> component .z of col j=2
    const float q = qwa * xw0[2].z + qwb * xw1[2].z + qwc * xw2[2].z;

    // s' = (ea + eb) * em * log2(e)   (scalar per output, shared by 16 taps)
    const float sp =
        (ea[c * 128 + w] + eb[c * 128 + h]) * em[(c * 128 + h) * 128 + w] * LOG2E;

    // embedding logits (log2 domain): tl = s' * v^2
    f4 tl[4];
#pragma unroll
    for (int j = 0; j < 4; ++j) tl[j] = (sp * vv[j]) * vv[j];

    f4 mm = vmax4(vmax4(tl[0], tl[1]), vmax4(tl[2], tl[3]));
    const float tmax = fmaxf(fmaxf(mm.x, mm.y), fmaxf(mm.z, mm.w));

    // e_t = 2^(tl - tmax); normalization folded into q below
    f4 e[4];
#pragma unroll
    for (int j = 0; j < 4; ++j) e[j] = vexp2(tl[j] - tmax);

    const float sum_e = hsum((e[0] + e[1]) + (e[2] + e[3]));
    const float qs = q * LOG2E * __builtin_amdgcn_rcpf(sum_e);

    // att logits z = qs * k * e  (|z| <~ 4 -> no max-subtraction needed)
    f4 p[4];
#pragma unroll
    for (int j = 0; j < 4; ++j) p[j] = vexp2((qs * kk[j]) * e[j]);

    f4 ps4 = (p[0] + p[1]) + (p[2] + p[3]);
    f4 pv4 = p[0] * vv[0] + p[1] * vv[1];
    pv4 = pv4 + (p[2] * vv[2] + p[3] * vv[3]);

    const float denom = hsum(ps4);
    const float numer = hsum(pv4);

    out[((b * 64 + c) * 128 + h) * 128 + w] =
        numer * __builtin_amdgcn_rcpf(denom);
  }
}

extern "C" void kernel_launch(void* const* d_in, const int* in_sizes, int n_in,
                              void* d_out, int out_size, void* d_ws, size_t ws_size,
                              hipStream_t stream) {
  const float* x  = (const float*)d_in[0];
  const float* qw = (const float*)d_in[1];
  const float* kw = (const float*)d_in[2];
  const float* vw = (const float*)d_in[3];
  const float* ea = (const float*)d_in[4];
  const float* eb = (const float*)d_in[5];
  const float* em = (const float*)d_in[6];
  float* out = (float*)d_out;

  stem_kernel<<<dim3(8 * 128), dim3(256), 0, stream>>>(x, qw, kw, vw, ea, eb, em, out);
}